// Round 1
// baseline (53.553 us; speedup 1.0000x reference)
//
#include <hip/hip_runtime.h>

#define N_NODES   200000
#define N_PATCHES 256
#define TSTEPS    12
#define NHID      16
#define HORIZON   12
#define GDIM      192            // NHID * TSTEPS
#define IN_DIM    204            // GDIM + TSTEPS

// ---------------------------------------------------------------------------
// Kernel 1: per-patch layer-1 partial:
//   patch_h[p][j] = b1[j] + sum_{i<192} patch_feat[p][i] * W1[i][j]
// where patch_feat[p][t*16+f] = mixer_x[0][t][p][f].
// Also builds wcomb[j][0..23] = { W1[192+t][j] (t=0..11), W2[j][o] (o=0..11) }
// so the hot kernel reads one contiguous 96-float slab per 4-j chunk.
// ---------------------------------------------------------------------------
__global__ __launch_bounds__(256) void patch_precompute(
    const float* __restrict__ mixer_x,   // (1,12,256,16)
    const float* __restrict__ W1,        // (204,204)
    const float* __restrict__ b1,        // (204)
    const float* __restrict__ W2,        // (204,12)
    float* __restrict__ patch_h,         // (256,204)
    float* __restrict__ wcomb)           // (204,24)
{
    __shared__ float xs[GDIM];
    const int p   = blockIdx.x;
    const int tid = threadIdx.x;

    if (tid < GDIM) {
        const int t = tid >> 4, f = tid & 15;
        xs[tid] = mixer_x[(t * N_PATCHES + p) * NHID + f];
    }
    __syncthreads();

    if (tid < IN_DIM) {
        float acc = b1[tid];
#pragma unroll 8
        for (int i = 0; i < GDIM; ++i)
            acc = fmaf(xs[i], W1[i * IN_DIM + tid], acc);
        patch_h[p * IN_DIM + tid] = acc;
    }

    if (p == 0) {
        for (int idx = tid; idx < IN_DIM * 24; idx += 256) {
            const int j = idx / 24;
            const int c = idx - j * 24;
            float v;
            if (c < 12) v = W1[(GDIM + c) * IN_DIM + j];
            else        v = W2[j * HORIZON + (c - 12)];
            wcomb[idx] = v;
        }
    }
}

// ---------------------------------------------------------------------------
// Kernel 2: per-node fused MLP. 2 nodes per thread.
//   h[j]  = relu(patch_h[p][j] + sum_t f[t] * wf[t][j])
//   out[o]= b2[o] + sum_j h[j] * W2[j][o]
// Weight reads (wcomb) are wave-uniform -> expect s_load (SMEM pipe).
// patch_h rows are 816 B (51 float4, 16B-aligned) served from L2 (209 KB tbl).
// ---------------------------------------------------------------------------
__global__ __launch_bounds__(256) void node_mlp(
    const float* __restrict__ features,   // (200000,12)
    const int*   __restrict__ node_patch, // (200000)
    const float* __restrict__ patch_h,    // (256,204)
    const float* __restrict__ wcomb,      // (204,24) viewed as (51,96)
    const float* __restrict__ b2,         // (12)
    float* __restrict__ out)              // (200000,12)
{
    const int tid = threadIdx.x;
    const int n0  = blockIdx.x * 512 + tid;
    const int n1  = n0 + 256;
    const bool v0 = (n0 < N_NODES);
    const bool v1 = (n1 < N_NODES);
    const int nn0 = v0 ? n0 : 0;
    const int nn1 = v1 ? n1 : 0;

    // node features (12 each) via 3x float4
    float f0[12], f1[12];
    {
        const float4* fp0 = (const float4*)(features + nn0 * 12);
        const float4* fp1 = (const float4*)(features + nn1 * 12);
#pragma unroll
        for (int q = 0; q < 3; ++q) {
            float4 a = fp0[q];
            f0[4*q+0] = a.x; f0[4*q+1] = a.y; f0[4*q+2] = a.z; f0[4*q+3] = a.w;
            float4 b = fp1[q];
            f1[4*q+0] = b.x; f1[4*q+1] = b.y; f1[4*q+2] = b.z; f1[4*q+3] = b.w;
        }
    }

    const int p0 = node_patch[nn0];
    const int p1 = node_patch[nn1];
    const float4* ph0 = (const float4*)(patch_h + p0 * IN_DIM);
    const float4* ph1 = (const float4*)(patch_h + p1 * IN_DIM);

    float o0[12], o1[12];
#pragma unroll
    for (int t = 0; t < 12; ++t) {
        const float bb = b2[t];
        o0[t] = bb; o1[t] = bb;
    }

    float4 a0 = ph0[0];
    float4 a1 = ph1[0];

    for (int jb = 0; jb < 51; ++jb) {
        const float4 c0 = a0;
        const float4 c1 = a1;
        if (jb < 50) {           // prefetch next chunk
            a0 = ph0[jb + 1];
            a1 = ph1[jb + 1];
        }
        const float cc0[4] = {c0.x, c0.y, c0.z, c0.w};
        const float cc1[4] = {c1.x, c1.y, c1.z, c1.w};
        const float* w = wcomb + jb * 96;
#pragma unroll
        for (int q = 0; q < 4; ++q) {
            const float* wq = w + q * 24;
            float h0 = cc0[q];
            float h1 = cc1[q];
#pragma unroll
            for (int t = 0; t < 12; ++t) {
                const float wv = wq[t];
                h0 = fmaf(f0[t], wv, h0);
                h1 = fmaf(f1[t], wv, h1);
            }
            h0 = fmaxf(h0, 0.0f);
            h1 = fmaxf(h1, 0.0f);
#pragma unroll
            for (int t = 0; t < 12; ++t) {
                const float wv = wq[12 + t];
                o0[t] = fmaf(h0, wv, o0[t]);
                o1[t] = fmaf(h1, wv, o1[t]);
            }
        }
    }

    if (v0) {
        float4* op = (float4*)(out + n0 * 12);
        op[0] = make_float4(o0[0], o0[1], o0[2],  o0[3]);
        op[1] = make_float4(o0[4], o0[5], o0[6],  o0[7]);
        op[2] = make_float4(o0[8], o0[9], o0[10], o0[11]);
    }
    if (v1) {
        float4* op = (float4*)(out + n1 * 12);
        op[0] = make_float4(o1[0], o1[1], o1[2],  o1[3]);
        op[1] = make_float4(o1[4], o1[5], o1[6],  o1[7]);
        op[2] = make_float4(o1[8], o1[9], o1[10], o1[11]);
    }
}

// ---------------------------------------------------------------------------
extern "C" void kernel_launch(void* const* d_in, const int* in_sizes, int n_in,
                              void* d_out, int out_size, void* d_ws, size_t ws_size,
                              hipStream_t stream) {
    const float* mixer_x    = (const float*)d_in[0];
    const float* features   = (const float*)d_in[1];
    const float* W1         = (const float*)d_in[2];
    const float* b1         = (const float*)d_in[3];
    const float* W2         = (const float*)d_in[4];
    const float* b2         = (const float*)d_in[5];
    const int*   node_patch = (const int*)d_in[6];
    float* out = (float*)d_out;

    float* patch_h = (float*)d_ws;                     // 256*204*4 = 208896 B
    float* wcomb   = patch_h + N_PATCHES * IN_DIM;     // +204*24*4 = 19584 B

    patch_precompute<<<N_PATCHES, 256, 0, stream>>>(mixer_x, W1, b1, W2,
                                                    patch_h, wcomb);

    const int nblocks = (N_NODES + 511) / 512;         // 391
    node_mlp<<<nblocks, 256, 0, stream>>>(features, node_patch, patch_h,
                                          wcomb, b2, out);
}